// Round 7
// baseline (389.914 us; speedup 1.0000x reference)
//
#include <hip/hip_runtime.h>

typedef __attribute__((ext_vector_type(4))) float f32x4;
typedef __attribute__((ext_vector_type(8))) short s16x8;
typedef __attribute__((ext_vector_type(8))) unsigned short u16x8;

#define AS1(p) ((const __attribute__((address_space(1))) void*)(p))
#define AS3(p) ((__attribute__((address_space(3))) void*)(p))

__device__ __forceinline__ unsigned short f2bf(float f) {
  unsigned u = __builtin_bit_cast(unsigned, f);
  u += 0x7fffu + ((u >> 16) & 1u);   // RNE; inputs are finite
  return (unsigned short)(u >> 16);
}
__device__ __forceinline__ float bf2f(unsigned short s) {
  unsigned u = ((unsigned)s) << 16;
  return __builtin_bit_cast(float, u);
}

// ---------------- fp32 -> bf16 cast (vectorized, grid-stride) ----------------
__global__ __launch_bounds__(256) void cast_bf16(const float* __restrict__ in,
                                                 unsigned short* __restrict__ out,
                                                 long n) {
  long i = ((long)blockIdx.x * 256 + threadIdx.x) * 4;
  long stride = (long)gridDim.x * 256 * 4;
  for (; i < n; i += stride) {
    float4 f = *(const float4*)(in + i);
    ushort4 o = { f2bf(f.x), f2bf(f.y), f2bf(f.z), f2bf(f.w) };
    *(ushort4*)(out + i) = o;
  }
}

// ---------------- hierarchical column cummax scan ----------------
__global__ __launch_bounds__(256) void scan_chunkmax(const float* __restrict__ x,
                                                     float* __restrict__ partial) {
  int col = blockIdx.x * 256 + threadIdx.x;
  int chunk = blockIdx.y;
  const float* p = x + (long)chunk * 64 * 1024 + col;
  float m = -INFINITY;
#pragma unroll 4
  for (int i = 0; i < 64; i++) m = fmaxf(m, p[(long)i * 1024]);
  partial[chunk * 1024 + col] = m;
}

__global__ __launch_bounds__(256) void scan_chunkscan(const float* __restrict__ partial,
                                                      float* __restrict__ prefix,
                                                      float* __restrict__ suffix) {
  int col = blockIdx.x * 256 + threadIdx.x;
  float run = -INFINITY;
  for (int c = 0; c < 128; c++) {
    prefix[c * 1024 + col] = run;
    run = fmaxf(run, partial[c * 1024 + col]);
  }
  run = -INFINITY;
  for (int c = 127; c >= 0; c--) {
    suffix[c * 1024 + col] = run;
    run = fmaxf(run, partial[c * 1024 + col]);
  }
}

__global__ __launch_bounds__(256) void scan_emit(const float* __restrict__ x,
                                                 const float* __restrict__ prefix,
                                                 const float* __restrict__ suffix,
                                                 unsigned short* __restrict__ h_in) {
  int col = blockIdx.x * 256 + threadIdx.x;
  int chunk = blockIdx.y;
  long r0 = (long)chunk * 64;
  float run = prefix[chunk * 1024 + col];
  for (int i = 0; i < 64; i++) {
    long row = r0 + i;
    float v = x[row * 1024 + col];
    unsigned short* hr = h_in + row * 3072;
    hr[col] = f2bf(v);
    hr[1024 + col] = f2bf(row == 0 ? 0.f : run);
    run = fmaxf(run, v);
  }
  float run2 = suffix[chunk * 1024 + col];
  for (int i = 63; i >= 0; i--) {
    long row = r0 + i;
    float v = x[row * 1024 + col];
    h_in[row * 3072 + 2048 + col] = f2bf(row == 8191 ? 0.f : run2);
    run2 = fmaxf(run2, v);
  }
}

// ============ 256x256 bf16 GEMM, m201-style 4-phase/K-tile: C = relu(A@B^T + bias) ============
// A [M,K], B [N,K] bf16 row-major. 512 thr = 8 waves (2M x 4N), per-wave out 128x64.
// BK=64. LDS: A 3x32K @0/32/64K, B 2x32K @96/128K = 160 KB.
// Swizzle (verified conflict-free r4): byte ^= (row&7)<<4; linear LDS dest +
//   inverse-swizzled global source + swizzled ds_read.
// r7 schedule — the m201 overlap mechanism: each phase's ds_reads are issued
//   right after the PREVIOUS phase's trailing barrier, while the matrix pipe is
//   still draining that phase's 128 issued MFMAs (s_barrier doesn't wait on MFMA
//   writeback). Phase p: {reads for p; stage 2; barrier; lgkmcnt(0); 16 MFMA
//   (m=2p,2p+1 over full K=64); barrier}. B (8 reads) at ph0 only, held all tile.
//   Stages: ph0/ph1 -> A(g+2) (region (g+2)%3, last read tile g-1, published at
//   its ph3 trailing barrier); ph2/ph3 -> B(g+2) (parity g&1 = B(g)'s region,
//   whose reads drained at ph0 lgkm0, published ph0 trailing barrier).
//   vmcnt(6) before ph2's trailing barrier publishes tile g+1 (6 = tile g+2's
//   stages issued so far); vmcnt(0) in the two tail tiles.
__global__ __launch_bounds__(512, 2) void gemm256_relu(
    const unsigned short* __restrict__ A, const unsigned short* __restrict__ B,
    unsigned short* __restrict__ C, const float* __restrict__ bias,
    int M, int N, int K) {
  extern __shared__ char smem[];
  const int NT = K >> 6;

  // XCD-chunked swizzle (grid %8 == 0)
  const int nwg = gridDim.x;
  const int cpx = nwg >> 3;
  const int bid = blockIdx.x;
  const int swz = (bid & 7) * cpx + (bid >> 3);
  const int tiles_m = M >> 8;
  const int tm = swz % tiles_m;
  const int tn = swz / tiles_m;
  const long brow = (long)tm * 256;
  const long bcol = (long)tn * 256;

  const int t = threadIdx.x;
  const int lane = t & 63, wv = t >> 6;
  const int wr = wv >> 2, wc = wv & 3;
  const int fr = lane & 15, fk = lane >> 4;

  const int srow = t >> 3;
  const int scol = 8 * ((t & 7) ^ ((t >> 3) & 7));
  const unsigned short* Asrc = A + (brow + srow) * (long)K + scol;
  const unsigned short* Bsrc = B + (bcol + srow) * (long)K + scol;
  const long hstep = (long)128 * K, lstep = (long)64 * K;

#define STAGE_A(j, reg, h, L)                                                  \
  __builtin_amdgcn_global_load_lds(AS1(Asrc + (h)*hstep + (L)*lstep + (j)*64), \
      AS3(smem + (reg)*32768 + (h)*16384 + (L)*8192 + t * 16), 16, 0, 0)
#define STAGE_B(j, h, L)                                                       \
  __builtin_amdgcn_global_load_lds(AS1(Bsrc + (h)*hstep + (L)*lstep + (j)*64), \
      AS3(smem + 98304 + ((j)&1) * 32768 + (h)*16384 + (L)*8192 + t * 16), 16, 0, 0)

  const int xr = (fr & 7) << 4;
  const char* ArdRow = smem + (wr * 128 + fr) * 128;
  const char* BrdRow = smem + 98304 + (wc * 64 + fr) * 128;
#define RD_A(ar_, m, kk) \
  (*(const s16x8*)(ArdRow + (ar_)*32768 + (m)*2048 + (((kk)*64 + fk * 16) ^ xr)))
#define RD_B(pb_, n, kk) \
  (*(const s16x8*)(BrdRow + (pb_)*32768 + (n)*2048 + (((kk)*64 + fk * 16) ^ xr)))

#define MFMA_PAIR(mi, a_)                                                      \
  _Pragma("unroll")                                                            \
  for (int n = 0; n < 4; ++n) {                                                \
    acc[(mi)][n] = __builtin_amdgcn_mfma_f32_16x16x32_bf16(                    \
        a_[0], bfr[n][0], acc[(mi)][n], 0, 0, 0);                              \
    acc[(mi)][n] = __builtin_amdgcn_mfma_f32_16x16x32_bf16(                    \
        a_[1], bfr[n][1], acc[(mi)][n], 0, 0, 0);                              \
  }

  f32x4 acc[8][4];
#pragma unroll
  for (int m = 0; m < 8; m++)
#pragma unroll
    for (int n = 0; n < 4; n++) acc[m][n] = (f32x4)0.f;

  // prologue: stage tile0 (A reg0, B pb0) then tile1 (A reg1, B pb1) = 16 loads
  STAGE_A(0, 0, 0, 0); STAGE_A(0, 0, 0, 1); STAGE_A(0, 0, 1, 0); STAGE_A(0, 0, 1, 1);
  STAGE_B(0, 0, 0); STAGE_B(0, 0, 1); STAGE_B(0, 1, 0); STAGE_B(0, 1, 1);
  STAGE_A(1, 1, 0, 0); STAGE_A(1, 1, 0, 1); STAGE_A(1, 1, 1, 0); STAGE_A(1, 1, 1, 1);
  STAGE_B(1, 0, 0); STAGE_B(1, 0, 1); STAGE_B(1, 1, 0); STAGE_B(1, 1, 1);
  asm volatile("s_waitcnt vmcnt(8)" ::: "memory");  // tile0 landed
  __builtin_amdgcn_s_barrier();                      // published to all waves

  s16x8 bfr[4][2];
  int ar = 0;  // g % 3
  for (int g = 0; g < NT; ++g) {
    const int pb = g & 1;
    int sr = ar + 2; if (sr >= 3) sr -= 3;  // (g+2) % 3
    const bool st = (g + 2 < NT);
#pragma unroll
    for (int p = 0; p < 4; ++p) {
      if (p == 0) {
#pragma unroll
        for (int n = 0; n < 4; ++n) {
          bfr[n][0] = RD_B(pb, n, 0);
          bfr[n][1] = RD_B(pb, n, 1);
        }
      }
      s16x8 av[2][2];
      av[0][0] = RD_A(ar, 2 * p, 0);     av[0][1] = RD_A(ar, 2 * p, 1);
      av[1][0] = RD_A(ar, 2 * p + 1, 0); av[1][1] = RD_A(ar, 2 * p + 1, 1);
      if (st) {
        if (p == 0) { STAGE_A(g + 2, sr, 0, 0); STAGE_A(g + 2, sr, 0, 1); }
        if (p == 1) { STAGE_A(g + 2, sr, 1, 0); STAGE_A(g + 2, sr, 1, 1); }
        if (p == 2) { STAGE_B(g + 2, 0, 0); STAGE_B(g + 2, 0, 1); }
        if (p == 3) { STAGE_B(g + 2, 1, 0); STAGE_B(g + 2, 1, 1); }
      }
      asm volatile("s_barrier" ::: "memory");
      asm volatile("s_waitcnt lgkmcnt(0)" ::: "memory");
      __builtin_amdgcn_sched_barrier(0);
      __builtin_amdgcn_s_setprio(1);
      MFMA_PAIR(2 * p, av[0])
      MFMA_PAIR(2 * p + 1, av[1])
      __builtin_amdgcn_s_setprio(0);
      if (p == 2 && g + 1 < NT) {
        if (st) asm volatile("s_waitcnt vmcnt(6)" ::: "memory");
        else    asm volatile("s_waitcnt vmcnt(0)" ::: "memory");
      }
      asm volatile("s_barrier" ::: "memory");
    }
    ar = (ar == 2) ? 0 : ar + 1;
  }

  // epilogue: C/D layout col=lane&15, row=(lane>>4)*4+reg
  float bi[4];
#pragma unroll
  for (int n = 0; n < 4; ++n) bi[n] = bias[bcol + wc * 64 + n * 16 + fr];
  const long orow = brow + wr * 128 + fk * 4;
  const long ocol = bcol + wc * 64 + fr;
#pragma unroll
  for (int m = 0; m < 8; ++m)
#pragma unroll
    for (int n = 0; n < 4; ++n)
#pragma unroll
      for (int r = 0; r < 4; ++r) {
        float v = acc[m][n][r] + bi[n];
        v = v > 0.f ? v : 0.f;
        C[(orow + m * 16 + r) * (long)N + ocol + n * 16] = f2bf(v);
      }
#undef STAGE_A
#undef STAGE_B
#undef RD_A
#undef RD_B
#undef MFMA_PAIR
}

// ---------------- m97-structure 128^2 bf16 GEMM (N=1024 GEMM2) ----------------
// LDS rows are 64 B: byte ^= ((row>>1)&3)<<4; source pre-swizzled to match.
__global__ __launch_bounds__(256) void gemm_bt2(const unsigned short* __restrict__ A,
                                                const unsigned short* __restrict__ B,
                                                float* __restrict__ Cf,
                                                const float* __restrict__ bias,
                                                const float* __restrict__ gamma,
                                                const float* __restrict__ resid,
                                                int M, int N, int K) {
  constexpr int BK = 32;
  __shared__ unsigned short As[128 * BK];
  __shared__ unsigned short Bs[128 * BK];
  const int tid = threadIdx.x;
  const int lane = tid & 63;
  const int wave = tid >> 6;
  const int wr = wave >> 1, wc = wave & 1;
  const long brow = (long)blockIdx.y * 128;
  const long bcol = (long)blockIdx.x * 128;

  const int scol = ((tid & 3) * 8) ^ ((((tid >> 3) & 3)) << 3);
  const unsigned short* Ag = A + (brow + (tid >> 2)) * (long)K + scol;
  const unsigned short* Bg = B + (bcol + (tid >> 2)) * (long)K + scol;
  const long rstep = (long)64 * K;

  f32x4 acc[4][4];
#pragma unroll
  for (int m = 0; m < 4; m++)
#pragma unroll
    for (int n = 0; n < 4; n++) acc[m][n] = (f32x4)0.f;

  const int fr = lane & 15, fk = lane >> 4;
  const int xr2 = ((fr >> 1) & 3) << 4;
  const char* Ard = (const char*)As + (wr * 64 + fr) * 64;
  const char* Brd = (const char*)Bs + (wc * 64 + fr) * 64;
#define RD2_A(m) (*(const s16x8*)(Ard + (m)*1024 + (fk * 16 ^ xr2)))
#define RD2_B(n) (*(const s16x8*)(Brd + (n)*1024 + (fk * 16 ^ xr2)))

  for (int k0 = 0; k0 < K; k0 += BK) {
    __syncthreads();
    __builtin_amdgcn_global_load_lds(AS1(Ag + k0), AS3((char*)As + tid * 16), 16, 0, 0);
    __builtin_amdgcn_global_load_lds(AS1(Ag + k0 + rstep), AS3((char*)As + 4096 + tid * 16), 16, 0, 0);
    __builtin_amdgcn_global_load_lds(AS1(Bg + k0), AS3((char*)Bs + tid * 16), 16, 0, 0);
    __builtin_amdgcn_global_load_lds(AS1(Bg + k0 + rstep), AS3((char*)Bs + 4096 + tid * 16), 16, 0, 0);
    __syncthreads();
    s16x8 af[4], bg[4];
#pragma unroll
    for (int m = 0; m < 4; m++) af[m] = RD2_A(m);
#pragma unroll
    for (int n = 0; n < 4; n++) bg[n] = RD2_B(n);
#pragma unroll
    for (int m = 0; m < 4; m++)
#pragma unroll
      for (int n = 0; n < 4; n++)
        acc[m][n] = __builtin_amdgcn_mfma_f32_16x16x32_bf16(af[m], bg[n], acc[m][n], 0, 0, 0);
  }
#undef RD2_A
#undef RD2_B

  const long orow = brow + wr * 64 + fk * 4;
  const long ocol = bcol + wc * 64 + fr;
#pragma unroll
  for (int m = 0; m < 4; m++) {
#pragma unroll
    for (int n = 0; n < 4; n++) {
      const long col = ocol + n * 16;
      const float bi = bias[col];
      const float ga = gamma[col];
#pragma unroll
      for (int r = 0; r < 4; r++) {
        const long row = orow + m * 16 + r;
        Cf[row * N + col] = (acc[m][n][r] + bi) * ga + resid[row * N + col];
      }
    }
  }
}

// ---------------- in-place LayerNorm over D=4096, one block per row ----------------
__global__ __launch_bounds__(256) void ln_inplace(unsigned short* __restrict__ h,
                                                  const float* __restrict__ w,
                                                  const float* __restrict__ b) {
  unsigned short* hp = h + (long)blockIdx.x * 4096;
  const int tid = threadIdx.x;
  u16x8 a0 = ((const u16x8*)hp)[tid * 2];
  u16x8 a1 = ((const u16x8*)hp)[tid * 2 + 1];
  float v[16];
#pragma unroll
  for (int j = 0; j < 8; j++) { v[j] = bf2f(a0[j]); v[8 + j] = bf2f(a1[j]); }
  float s = 0.f, q = 0.f;
#pragma unroll
  for (int j = 0; j < 16; j++) { s += v[j]; q += v[j] * v[j]; }
#pragma unroll
  for (int off = 32; off; off >>= 1) {
    s += __shfl_xor(s, off, 64);
    q += __shfl_xor(q, off, 64);
  }
  __shared__ float ss[4], sq[4];
  const int wv = tid >> 6;
  if ((tid & 63) == 0) { ss[wv] = s; sq[wv] = q; }
  __syncthreads();
  s = ss[0] + ss[1] + ss[2] + ss[3];
  q = sq[0] + sq[1] + sq[2] + sq[3];
  const float mu = s * (1.f / 4096.f);
  const float var = q * (1.f / 4096.f) - mu * mu;
  const float rs = rsqrtf(var + 1e-6f);
  u16x8 o0, o1;
#pragma unroll
  for (int j = 0; j < 8; j++) {
    int c0 = tid * 16 + j, c1 = c0 + 8;
    o0[j] = f2bf((v[j] - mu) * rs * w[c0] + b[c0]);
    o1[j] = f2bf((v[8 + j] - mu) * rs * w[c1] + b[c1]);
  }
  ((u16x8*)hp)[tid * 2] = o0;
  ((u16x8*)hp)[tid * 2 + 1] = o1;
}

extern "C" void kernel_launch(void* const* d_in, const int* in_sizes, int n_in,
                              void* d_out, int out_size, void* d_ws, size_t ws_size,
                              hipStream_t stream) {
  const float* x     = (const float*)d_in[0];
  const float* W1    = (const float*)d_in[1];
  const float* b1    = (const float*)d_in[2];
  const float* ln_w  = (const float*)d_in[3];
  const float* ln_b  = (const float*)d_in[4];
  const float* W2    = (const float*)d_in[5];
  const float* b2    = (const float*)d_in[6];
  const float* gamma = (const float*)d_in[7];
  float* out = (float*)d_out;

  const int Nr = 8192, DIM = 1024, DFF = 4096, K1 = 3072;

  unsigned short* W1b  = (unsigned short*)d_ws;
  unsigned short* W2b  = W1b + (long)DFF * K1;
  unsigned short* h_in = W2b + (long)DIM * DFF;
  unsigned short* h_act = h_in + (long)Nr * K1;
  float* partial = (float*)(h_act + (long)Nr * DFF);
  float* prefix  = partial + 128 * 1024;
  float* suffix  = prefix + 128 * 1024;

  hipFuncSetAttribute((const void*)gemm256_relu,
                      hipFuncAttributeMaxDynamicSharedMemorySize, 163840);

  cast_bf16<<<2048, 256, 0, stream>>>(W1, W1b, (long)DFF * K1);
  cast_bf16<<<1024, 256, 0, stream>>>(W2, W2b, (long)DIM * DFF);

  scan_chunkmax<<<dim3(4, 128), 256, 0, stream>>>(x, partial);
  scan_chunkscan<<<4, 256, 0, stream>>>(partial, prefix, suffix);
  scan_emit<<<dim3(4, 128), 256, 0, stream>>>(x, prefix, suffix, h_in);

  // GEMM1: h_act = relu(h_in @ W1^T + b1)  — 256^2 4-phase/K-tile, grid 32x16=512
  gemm256_relu<<<512, 512, 163840, stream>>>(h_in, W1b, h_act, b1, Nr, DFF, K1);

  ln_inplace<<<Nr, 256, 0, stream>>>(h_act, ln_w, ln_b);

  // GEMM2: out = (h_act @ W2^T + b2) * gamma + x  — m97 128^2
  gemm_bt2<<<dim3(DIM / 128, Nr / 128), 256, 0, stream>>>(
      h_act, W2b, out, b2, gamma, x, Nr, DIM, DFF);
}

// Round 8
// 387.384 us; speedup vs baseline: 1.0065x; 1.0065x over previous
//
#include <hip/hip_runtime.h>

typedef __attribute__((ext_vector_type(4))) float f32x4;
typedef __attribute__((ext_vector_type(8))) short s16x8;
typedef __attribute__((ext_vector_type(8))) unsigned short u16x8;

#define AS1(p) ((const __attribute__((address_space(1))) void*)(p))
#define AS3(p) ((__attribute__((address_space(3))) void*)(p))

__device__ __forceinline__ unsigned short f2bf(float f) {
  unsigned u = __builtin_bit_cast(unsigned, f);
  u += 0x7fffu + ((u >> 16) & 1u);   // RNE; inputs are finite
  return (unsigned short)(u >> 16);
}
__device__ __forceinline__ float bf2f(unsigned short s) {
  unsigned u = ((unsigned)s) << 16;
  return __builtin_bit_cast(float, u);
}

// ---------------- fp32 -> bf16 cast (vectorized, grid-stride) ----------------
__global__ __launch_bounds__(256) void cast_bf16(const float* __restrict__ in,
                                                 unsigned short* __restrict__ out,
                                                 long n) {
  long i = ((long)blockIdx.x * 256 + threadIdx.x) * 4;
  long stride = (long)gridDim.x * 256 * 4;
  for (; i < n; i += stride) {
    float4 f = *(const float4*)(in + i);
    ushort4 o = { f2bf(f.x), f2bf(f.y), f2bf(f.z), f2bf(f.w) };
    *(ushort4*)(out + i) = o;
  }
}

// ---------------- hierarchical column cummax scan ----------------
__global__ __launch_bounds__(256) void scan_chunkmax(const float* __restrict__ x,
                                                     float* __restrict__ partial) {
  int col = blockIdx.x * 256 + threadIdx.x;
  int chunk = blockIdx.y;
  const float* p = x + (long)chunk * 64 * 1024 + col;
  float m = -INFINITY;
#pragma unroll 4
  for (int i = 0; i < 64; i++) m = fmaxf(m, p[(long)i * 1024]);
  partial[chunk * 1024 + col] = m;
}

__global__ __launch_bounds__(256) void scan_chunkscan(const float* __restrict__ partial,
                                                      float* __restrict__ prefix,
                                                      float* __restrict__ suffix) {
  int col = blockIdx.x * 256 + threadIdx.x;
  float run = -INFINITY;
  for (int c = 0; c < 128; c++) {
    prefix[c * 1024 + col] = run;
    run = fmaxf(run, partial[c * 1024 + col]);
  }
  run = -INFINITY;
  for (int c = 127; c >= 0; c--) {
    suffix[c * 1024 + col] = run;
    run = fmaxf(run, partial[c * 1024 + col]);
  }
}

__global__ __launch_bounds__(256) void scan_emit(const float* __restrict__ x,
                                                 const float* __restrict__ prefix,
                                                 const float* __restrict__ suffix,
                                                 unsigned short* __restrict__ h_in) {
  int col = blockIdx.x * 256 + threadIdx.x;
  int chunk = blockIdx.y;
  long r0 = (long)chunk * 64;
  float run = prefix[chunk * 1024 + col];
  for (int i = 0; i < 64; i++) {
    long row = r0 + i;
    float v = x[row * 1024 + col];
    unsigned short* hr = h_in + row * 3072;
    hr[col] = f2bf(v);
    hr[1024 + col] = f2bf(row == 0 ? 0.f : run);
    run = fmaxf(run, v);
  }
  float run2 = suffix[chunk * 1024 + col];
  for (int i = 63; i >= 0; i--) {
    long row = r0 + i;
    float v = x[row * 1024 + col];
    h_in[row * 3072 + 2048 + col] = f2bf(row == 8191 ? 0.f : run2);
    run2 = fmaxf(run2, v);
  }
}

// ============ 256x256 bf16 GEMM, r8: one-phase-ahead A-read pipeline ============
// A [M,K], B [N,K] bf16 row-major. 512 thr = 8 waves (2M x 4N), per-wave out 128x64.
// BK=64. LDS: A 3x32K @0/32/64K, B 2x32K @96/128K = 160 KB.
// Swizzle (verified 0-conflict): byte ^= (row&7)<<4, both-sides.
// r8 mechanism: r7's reads were issued ~0 cy ahead of their lgkmcnt(0) -> LDS
// and MFMA pipes ran serially (measured 1269cy/phase = 578 read + 516 MFMA +
// 175 bar). Now phase p consumes A-frags read during phase p-1 (register sets
// ping-pong on p&1); reads for p+1 drain under p's MFMA + barrier. Cross-tile:
// ph3 pre-reads A(g+1,m0/m1) — tile g+1 is published at ph2(g) (vmcnt+barrier).
// B is read at ph0 (burst; ~150cy residual stall) to stay under the VGPR cap.
// Stages/vmcnt identical to r7: p0/p1 stage A(g+2)->(g+2)%3, p2/p3 stage
// B(g+2)->parity, vmcnt(6 | 0) before ph2's trailing barrier.
__global__ __launch_bounds__(512, 2) void gemm256_relu(
    const unsigned short* __restrict__ A, const unsigned short* __restrict__ B,
    unsigned short* __restrict__ C, const float* __restrict__ bias,
    int M, int N, int K) {
  extern __shared__ char smem[];
  const int NT = K >> 6;

  // XCD-chunked swizzle (grid %8 == 0)
  const int nwg = gridDim.x;
  const int cpx = nwg >> 3;
  const int bid = blockIdx.x;
  const int swz = (bid & 7) * cpx + (bid >> 3);
  const int tiles_m = M >> 8;
  const int tm = swz % tiles_m;
  const int tn = swz / tiles_m;
  const long brow = (long)tm * 256;
  const long bcol = (long)tn * 256;

  const int t = threadIdx.x;
  const int lane = t & 63, wv = t >> 6;
  const int wr = wv >> 2, wc = wv & 3;
  const int fr = lane & 15, fk = lane >> 4;

  const int srow = t >> 3;
  const int scol = 8 * ((t & 7) ^ ((t >> 3) & 7));
  const unsigned short* Asrc = A + (brow + srow) * (long)K + scol;
  const unsigned short* Bsrc = B + (bcol + srow) * (long)K + scol;
  const long hstep = (long)128 * K, lstep = (long)64 * K;

#define STAGE_A(j, reg, h, L)                                                  \
  __builtin_amdgcn_global_load_lds(AS1(Asrc + (h)*hstep + (L)*lstep + (j)*64), \
      AS3(smem + (reg)*32768 + (h)*16384 + (L)*8192 + t * 16), 16, 0, 0)
#define STAGE_B(j, h, L)                                                       \
  __builtin_amdgcn_global_load_lds(AS1(Bsrc + (h)*hstep + (L)*lstep + (j)*64), \
      AS3(smem + 98304 + ((j)&1) * 32768 + (h)*16384 + (L)*8192 + t * 16), 16, 0, 0)

  const int xr = (fr & 7) << 4;
  const char* ArdRow = smem + (wr * 128 + fr) * 128;
  const char* BrdRow = smem + 98304 + (wc * 64 + fr) * 128;
#define RD_A(ar_, m, kk) \
  (*(const s16x8*)(ArdRow + (ar_)*32768 + (m)*2048 + (((kk)*64 + fk * 16) ^ xr)))
#define RD_B(pb_, n, kk) \
  (*(const s16x8*)(BrdRow + (pb_)*32768 + (n)*2048 + (((kk)*64 + fk * 16) ^ xr)))

#define MFMA_PAIR(mi, a_)                                                      \
  _Pragma("unroll")                                                            \
  for (int n = 0; n < 4; ++n) {                                                \
    acc[(mi)][n] = __builtin_amdgcn_mfma_f32_16x16x32_bf16(                    \
        a_[0], bfr[n][0], acc[(mi)][n], 0, 0, 0);                              \
    acc[(mi)][n] = __builtin_amdgcn_mfma_f32_16x16x32_bf16(                    \
        a_[1], bfr[n][1], acc[(mi)][n], 0, 0, 0);                              \
  }

  f32x4 acc[8][4];
#pragma unroll
  for (int m = 0; m < 8; m++)
#pragma unroll
    for (int n = 0; n < 4; n++) acc[m][n] = (f32x4)0.f;

  // prologue: stage tile0 (A reg0, B pb0) then tile1 (A reg1, B pb1) = 16 loads
  STAGE_A(0, 0, 0, 0); STAGE_A(0, 0, 0, 1); STAGE_A(0, 0, 1, 0); STAGE_A(0, 0, 1, 1);
  STAGE_B(0, 0, 0); STAGE_B(0, 0, 1); STAGE_B(0, 1, 0); STAGE_B(0, 1, 1);
  STAGE_A(1, 1, 0, 0); STAGE_A(1, 1, 0, 1); STAGE_A(1, 1, 1, 0); STAGE_A(1, 1, 1, 1);
  STAGE_B(1, 0, 0); STAGE_B(1, 0, 1); STAGE_B(1, 1, 0); STAGE_B(1, 1, 1);
  asm volatile("s_waitcnt vmcnt(8)" ::: "memory");  // tile0 landed
  __builtin_amdgcn_s_barrier();                      // published to all waves

  s16x8 bfr[4][2];
  s16x8 ap[2][2][2];  // [set][i][kk] — ping-pong on phase parity
  ap[0][0][0] = RD_A(0, 0, 0); ap[0][0][1] = RD_A(0, 0, 1);
  ap[0][1][0] = RD_A(0, 1, 0); ap[0][1][1] = RD_A(0, 1, 1);

  int ar = 0;  // g % 3
  for (int g = 0; g < NT; ++g) {
    const int pb = g & 1;
    int sr = ar + 2; if (sr >= 3) sr -= 3;   // (g+2) % 3
    int nar = ar + 1; if (nar >= 3) nar = 0; // (g+1) % 3
    const bool st = (g + 2 < NT);
#pragma unroll
    for (int p = 0; p < 4; ++p) {
      const int cs = p & 1, ns = cs ^ 1;
      if (p == 0) {
#pragma unroll
        for (int n = 0; n < 4; ++n) {
          bfr[n][0] = RD_B(pb, n, 0);
          bfr[n][1] = RD_B(pb, n, 1);
        }
      }
      asm volatile("s_waitcnt lgkmcnt(0)" ::: "memory");
      __builtin_amdgcn_sched_barrier(0);
      __builtin_amdgcn_s_setprio(1);
      MFMA_PAIR(2 * p, ap[cs][0])
      MFMA_PAIR(2 * p + 1, ap[cs][1])
      __builtin_amdgcn_s_setprio(0);
      // read-ahead for the next phase (drains under this phase's MFMA + barrier)
      if (p < 3) {
        ap[ns][0][0] = RD_A(ar, 2 * p + 2, 0); ap[ns][0][1] = RD_A(ar, 2 * p + 2, 1);
        ap[ns][1][0] = RD_A(ar, 2 * p + 3, 0); ap[ns][1][1] = RD_A(ar, 2 * p + 3, 1);
      } else if (g + 1 < NT) {  // tile g+1 published at ph2's vmcnt+barrier
        ap[ns][0][0] = RD_A(nar, 0, 0); ap[ns][0][1] = RD_A(nar, 0, 1);
        ap[ns][1][0] = RD_A(nar, 1, 0); ap[ns][1][1] = RD_A(nar, 1, 1);
      }
      if (st) {
        if (p == 0) { STAGE_A(g + 2, sr, 0, 0); STAGE_A(g + 2, sr, 0, 1); }
        if (p == 1) { STAGE_A(g + 2, sr, 1, 0); STAGE_A(g + 2, sr, 1, 1); }
        if (p == 2) { STAGE_B(g + 2, 0, 0); STAGE_B(g + 2, 0, 1); }
        if (p == 3) { STAGE_B(g + 2, 1, 0); STAGE_B(g + 2, 1, 1); }
      }
      if (p == 2 && g + 1 < NT) {
        if (st) asm volatile("s_waitcnt vmcnt(6)" ::: "memory");
        else    asm volatile("s_waitcnt vmcnt(0)" ::: "memory");
      }
      asm volatile("s_barrier" ::: "memory");
    }
    ar = nar;
  }

  // epilogue: C/D layout col=lane&15, row=(lane>>4)*4+reg
  float bi[4];
#pragma unroll
  for (int n = 0; n < 4; ++n) bi[n] = bias[bcol + wc * 64 + n * 16 + fr];
  const long orow = brow + wr * 128 + fk * 4;
  const long ocol = bcol + wc * 64 + fr;
#pragma unroll
  for (int m = 0; m < 8; ++m)
#pragma unroll
    for (int n = 0; n < 4; ++n)
#pragma unroll
      for (int r = 0; r < 4; ++r) {
        float v = acc[m][n][r] + bi[n];
        v = v > 0.f ? v : 0.f;
        C[(orow + m * 16 + r) * (long)N + ocol + n * 16] = f2bf(v);
      }
#undef STAGE_A
#undef STAGE_B
#undef RD_A
#undef RD_B
#undef MFMA_PAIR
}

// ---------------- m97-structure 128^2 bf16 GEMM (N=1024 GEMM2) ----------------
// LDS rows are 64 B: byte ^= ((row>>1)&3)<<4; source pre-swizzled to match.
__global__ __launch_bounds__(256) void gemm_bt2(const unsigned short* __restrict__ A,
                                                const unsigned short* __restrict__ B,
                                                float* __restrict__ Cf,
                                                const float* __restrict__ bias,
                                                const float* __restrict__ gamma,
                                                const float* __restrict__ resid,
                                                int M, int N, int K) {
  constexpr int BK = 32;
  __shared__ unsigned short As[128 * BK];
  __shared__ unsigned short Bs[128 * BK];
  const int tid = threadIdx.x;
  const int lane = tid & 63;
  const int wave = tid >> 6;
  const int wr = wave >> 1, wc = wave & 1;
  const long brow = (long)blockIdx.y * 128;
  const long bcol = (long)blockIdx.x * 128;

  const int scol = ((tid & 3) * 8) ^ ((((tid >> 3) & 3)) << 3);
  const unsigned short* Ag = A + (brow + (tid >> 2)) * (long)K + scol;
  const unsigned short* Bg = B + (bcol + (tid >> 2)) * (long)K + scol;
  const long rstep = (long)64 * K;

  f32x4 acc[4][4];
#pragma unroll
  for (int m = 0; m < 4; m++)
#pragma unroll
    for (int n = 0; n < 4; n++) acc[m][n] = (f32x4)0.f;

  const int fr = lane & 15, fk = lane >> 4;
  const int xr2 = ((fr >> 1) & 3) << 4;
  const char* Ard = (const char*)As + (wr * 64 + fr) * 64;
  const char* Brd = (const char*)Bs + (wc * 64 + fr) * 64;
#define RD2_A(m) (*(const s16x8*)(Ard + (m)*1024 + (fk * 16 ^ xr2)))
#define RD2_B(n) (*(const s16x8*)(Brd + (n)*1024 + (fk * 16 ^ xr2)))

  for (int k0 = 0; k0 < K; k0 += BK) {
    __syncthreads();
    __builtin_amdgcn_global_load_lds(AS1(Ag + k0), AS3((char*)As + tid * 16), 16, 0, 0);
    __builtin_amdgcn_global_load_lds(AS1(Ag + k0 + rstep), AS3((char*)As + 4096 + tid * 16), 16, 0, 0);
    __builtin_amdgcn_global_load_lds(AS1(Bg + k0), AS3((char*)Bs + tid * 16), 16, 0, 0);
    __builtin_amdgcn_global_load_lds(AS1(Bg + k0 + rstep), AS3((char*)Bs + 4096 + tid * 16), 16, 0, 0);
    __syncthreads();
    s16x8 af[4], bg[4];
#pragma unroll
    for (int m = 0; m < 4; m++) af[m] = RD2_A(m);
#pragma unroll
    for (int n = 0; n < 4; n++) bg[n] = RD2_B(n);
#pragma unroll
    for (int m = 0; m < 4; m++)
#pragma unroll
      for (int n = 0; n < 4; n++)
        acc[m][n] = __builtin_amdgcn_mfma_f32_16x16x32_bf16(af[m], bg[n], acc[m][n], 0, 0, 0);
  }
#undef RD2_A
#undef RD2_B

  const long orow = brow + wr * 64 + fk * 4;
  const long ocol = bcol + wc * 64 + fr;
#pragma unroll
  for (int m = 0; m < 4; m++) {
#pragma unroll
    for (int n = 0; n < 4; n++) {
      const long col = ocol + n * 16;
      const float bi = bias[col];
      const float ga = gamma[col];
#pragma unroll
      for (int r = 0; r < 4; r++) {
        const long row = orow + m * 16 + r;
        Cf[row * N + col] = (acc[m][n][r] + bi) * ga + resid[row * N + col];
      }
    }
  }
}

// ---------------- in-place LayerNorm over D=4096, one block per row ----------------
__global__ __launch_bounds__(256) void ln_inplace(unsigned short* __restrict__ h,
                                                  const float* __restrict__ w,
                                                  const float* __restrict__ b) {
  unsigned short* hp = h + (long)blockIdx.x * 4096;
  const int tid = threadIdx.x;
  u16x8 a0 = ((const u16x8*)hp)[tid * 2];
  u16x8 a1 = ((const u16x8*)hp)[tid * 2 + 1];
  float v[16];
#pragma unroll
  for (int j = 0; j < 8; j++) { v[j] = bf2f(a0[j]); v[8 + j] = bf2f(a1[j]); }
  float s = 0.f, q = 0.f;
#pragma unroll
  for (int j = 0; j < 16; j++) { s += v[j]; q += v[j] * v[j]; }
#pragma unroll
  for (int off = 32; off; off >>= 1) {
    s += __shfl_xor(s, off, 64);
    q += __shfl_xor(q, off, 64);
  }
  __shared__ float ss[4], sq[4];
  const int wv = tid >> 6;
  if ((tid & 63) == 0) { ss[wv] = s; sq[wv] = q; }
  __syncthreads();
  s = ss[0] + ss[1] + ss[2] + ss[3];
  q = sq[0] + sq[1] + sq[2] + sq[3];
  const float mu = s * (1.f / 4096.f);
  const float var = q * (1.f / 4096.f) - mu * mu;
  const float rs = rsqrtf(var + 1e-6f);
  u16x8 o0, o1;
#pragma unroll
  for (int j = 0; j < 8; j++) {
    int c0 = tid * 16 + j, c1 = c0 + 8;
    o0[j] = f2bf((v[j] - mu) * rs * w[c0] + b[c0]);
    o1[j] = f2bf((v[8 + j] - mu) * rs * w[c1] + b[c1]);
  }
  ((u16x8*)hp)[tid * 2] = o0;
  ((u16x8*)hp)[tid * 2 + 1] = o1;
}

extern "C" void kernel_launch(void* const* d_in, const int* in_sizes, int n_in,
                              void* d_out, int out_size, void* d_ws, size_t ws_size,
                              hipStream_t stream) {
  const float* x     = (const float*)d_in[0];
  const float* W1    = (const float*)d_in[1];
  const float* b1    = (const float*)d_in[2];
  const float* ln_w  = (const float*)d_in[3];
  const float* ln_b  = (const float*)d_in[4];
  const float* W2    = (const float*)d_in[5];
  const float* b2    = (const float*)d_in[6];
  const float* gamma = (const float*)d_in[7];
  float* out = (float*)d_out;

  const int Nr = 8192, DIM = 1024, DFF = 4096, K1 = 3072;

  unsigned short* W1b  = (unsigned short*)d_ws;
  unsigned short* W2b  = W1b + (long)DFF * K1;
  unsigned short* h_in = W2b + (long)DIM * DFF;
  unsigned short* h_act = h_in + (long)Nr * K1;
  float* partial = (float*)(h_act + (long)Nr * DFF);
  float* prefix  = partial + 128 * 1024;
  float* suffix  = prefix + 128 * 1024;

  hipFuncSetAttribute((const void*)gemm256_relu,
                      hipFuncAttributeMaxDynamicSharedMemorySize, 163840);

  cast_bf16<<<2048, 256, 0, stream>>>(W1, W1b, (long)DFF * K1);
  cast_bf16<<<1024, 256, 0, stream>>>(W2, W2b, (long)DIM * DFF);

  scan_chunkmax<<<dim3(4, 128), 256, 0, stream>>>(x, partial);
  scan_chunkscan<<<4, 256, 0, stream>>>(partial, prefix, suffix);
  scan_emit<<<dim3(4, 128), 256, 0, stream>>>(x, prefix, suffix, h_in);

  // GEMM1: h_act = relu(h_in @ W1^T + b1)  — 256^2 read-pipelined, grid 32x16=512
  gemm256_relu<<<512, 512, 163840, stream>>>(h_in, W1b, h_act, b1, Nr, DFF, K1);

  ln_inplace<<<Nr, 256, 0, stream>>>(h_act, ln_w, ln_b);

  // GEMM2: out = (h_act @ W2^T + b2) * gamma + x  — m97 128^2
  gemm_bt2<<<dim3(DIM / 128, Nr / 128), 256, 0, stream>>>(
      h_act, W2b, out, b2, gamma, x, Nr, DIM, DFF);
}

// Round 9
// 361.506 us; speedup vs baseline: 1.0786x; 1.0716x over previous
//
#include <hip/hip_runtime.h>

typedef __attribute__((ext_vector_type(4))) float f32x4;
typedef __attribute__((ext_vector_type(8))) short s16x8;
typedef __attribute__((ext_vector_type(8))) unsigned short u16x8;

#define AS1(p) ((const __attribute__((address_space(1))) void*)(p))
#define AS3(p) ((__attribute__((address_space(3))) void*)(p))

__device__ __forceinline__ unsigned short f2bf(float f) {
  unsigned u = __builtin_bit_cast(unsigned, f);
  u += 0x7fffu + ((u >> 16) & 1u);   // RNE; inputs are finite
  return (unsigned short)(u >> 16);
}
__device__ __forceinline__ float bf2f(unsigned short s) {
  unsigned u = ((unsigned)s) << 16;
  return __builtin_bit_cast(float, u);
}

// ---------------- fp32 -> bf16 cast (vectorized, grid-stride) ----------------
__global__ __launch_bounds__(256) void cast_bf16(const float* __restrict__ in,
                                                 unsigned short* __restrict__ out,
                                                 long n) {
  long i = ((long)blockIdx.x * 256 + threadIdx.x) * 4;
  long stride = (long)gridDim.x * 256 * 4;
  for (; i < n; i += stride) {
    float4 f = *(const float4*)(in + i);
    ushort4 o = { f2bf(f.x), f2bf(f.y), f2bf(f.z), f2bf(f.w) };
    *(ushort4*)(out + i) = o;
  }
}

// ---------------- hierarchical column cummax scan ----------------
__global__ __launch_bounds__(256) void scan_chunkmax(const float* __restrict__ x,
                                                     float* __restrict__ partial) {
  int col = blockIdx.x * 256 + threadIdx.x;
  int chunk = blockIdx.y;
  const float* p = x + (long)chunk * 64 * 1024 + col;
  float m = -INFINITY;
#pragma unroll 4
  for (int i = 0; i < 64; i++) m = fmaxf(m, p[(long)i * 1024]);
  partial[chunk * 1024 + col] = m;
}

__global__ __launch_bounds__(256) void scan_chunkscan(const float* __restrict__ partial,
                                                      float* __restrict__ prefix,
                                                      float* __restrict__ suffix) {
  int col = blockIdx.x * 256 + threadIdx.x;
  float run = -INFINITY;
  for (int c = 0; c < 128; c++) {
    prefix[c * 1024 + col] = run;
    run = fmaxf(run, partial[c * 1024 + col]);
  }
  run = -INFINITY;
  for (int c = 127; c >= 0; c--) {
    suffix[c * 1024 + col] = run;
    run = fmaxf(run, partial[c * 1024 + col]);
  }
}

__global__ __launch_bounds__(256) void scan_emit(const float* __restrict__ x,
                                                 const float* __restrict__ prefix,
                                                 const float* __restrict__ suffix,
                                                 unsigned short* __restrict__ h_in) {
  int col = blockIdx.x * 256 + threadIdx.x;
  int chunk = blockIdx.y;
  long r0 = (long)chunk * 64;
  float run = prefix[chunk * 1024 + col];
  for (int i = 0; i < 64; i++) {
    long row = r0 + i;
    float v = x[row * 1024 + col];
    unsigned short* hr = h_in + row * 3072;
    hr[col] = f2bf(v);
    hr[1024 + col] = f2bf(row == 0 ? 0.f : run);
    run = fmaxf(run, v);
  }
  float run2 = suffix[chunk * 1024 + col];
  for (int i = 63; i >= 0; i--) {
    long row = r0 + i;
    float v = x[row * 1024 + col];
    h_in[row * 3072 + 2048 + col] = f2bf(row == 8191 ? 0.f : run2);
    run2 = fmaxf(run2, v);
  }
}

// ============ 256x256 bf16 GEMM (r8 structure, best measured): C = relu(A@B^T + bias) ============
__global__ __launch_bounds__(512, 2) void gemm256_relu(
    const unsigned short* __restrict__ A, const unsigned short* __restrict__ B,
    unsigned short* __restrict__ C, const float* __restrict__ bias,
    int M, int N, int K) {
  extern __shared__ char smem[];
  const int NT = K >> 6;

  const int nwg = gridDim.x;
  const int cpx = nwg >> 3;
  const int bid = blockIdx.x;
  const int swz = (bid & 7) * cpx + (bid >> 3);
  const int tiles_m = M >> 8;
  const int tm = swz % tiles_m;
  const int tn = swz / tiles_m;
  const long brow = (long)tm * 256;
  const long bcol = (long)tn * 256;

  const int t = threadIdx.x;
  const int lane = t & 63, wv = t >> 6;
  const int wr = wv >> 2, wc = wv & 3;
  const int fr = lane & 15, fk = lane >> 4;

  const int srow = t >> 3;
  const int scol = 8 * ((t & 7) ^ ((t >> 3) & 7));
  const unsigned short* Asrc = A + (brow + srow) * (long)K + scol;
  const unsigned short* Bsrc = B + (bcol + srow) * (long)K + scol;
  const long hstep = (long)128 * K, lstep = (long)64 * K;

#define STAGE_A(j, reg, h, L)                                                  \
  __builtin_amdgcn_global_load_lds(AS1(Asrc + (h)*hstep + (L)*lstep + (j)*64), \
      AS3(smem + (reg)*32768 + (h)*16384 + (L)*8192 + t * 16), 16, 0, 0)
#define STAGE_B(j, h, L)                                                       \
  __builtin_amdgcn_global_load_lds(AS1(Bsrc + (h)*hstep + (L)*lstep + (j)*64), \
      AS3(smem + 98304 + ((j)&1) * 32768 + (h)*16384 + (L)*8192 + t * 16), 16, 0, 0)

  const int xr = (fr & 7) << 4;
  const char* ArdRow = smem + (wr * 128 + fr) * 128;
  const char* BrdRow = smem + 98304 + (wc * 64 + fr) * 128;
#define RD_A(ar_, m, kk) \
  (*(const s16x8*)(ArdRow + (ar_)*32768 + (m)*2048 + (((kk)*64 + fk * 16) ^ xr)))
#define RD_B(pb_, n, kk) \
  (*(const s16x8*)(BrdRow + (pb_)*32768 + (n)*2048 + (((kk)*64 + fk * 16) ^ xr)))

#define MFMA_PAIR(mi, a_)                                                      \
  _Pragma("unroll")                                                            \
  for (int n = 0; n < 4; ++n) {                                                \
    acc[(mi)][n] = __builtin_amdgcn_mfma_f32_16x16x32_bf16(                    \
        a_[0], bfr[n][0], acc[(mi)][n], 0, 0, 0);                              \
    acc[(mi)][n] = __builtin_amdgcn_mfma_f32_16x16x32_bf16(                    \
        a_[1], bfr[n][1], acc[(mi)][n], 0, 0, 0);                              \
  }

  f32x4 acc[8][4];
#pragma unroll
  for (int m = 0; m < 8; m++)
#pragma unroll
    for (int n = 0; n < 4; n++) acc[m][n] = (f32x4)0.f;

  STAGE_A(0, 0, 0, 0); STAGE_A(0, 0, 0, 1); STAGE_A(0, 0, 1, 0); STAGE_A(0, 0, 1, 1);
  STAGE_B(0, 0, 0); STAGE_B(0, 0, 1); STAGE_B(0, 1, 0); STAGE_B(0, 1, 1);
  STAGE_A(1, 1, 0, 0); STAGE_A(1, 1, 0, 1); STAGE_A(1, 1, 1, 0); STAGE_A(1, 1, 1, 1);
  STAGE_B(1, 0, 0); STAGE_B(1, 0, 1); STAGE_B(1, 1, 0); STAGE_B(1, 1, 1);
  asm volatile("s_waitcnt vmcnt(8)" ::: "memory");
  __builtin_amdgcn_s_barrier();

  s16x8 bfr[4][2];
  s16x8 ap[2][2][2];
  ap[0][0][0] = RD_A(0, 0, 0); ap[0][0][1] = RD_A(0, 0, 1);
  ap[0][1][0] = RD_A(0, 1, 0); ap[0][1][1] = RD_A(0, 1, 1);

  int ar = 0;
  for (int g = 0; g < NT; ++g) {
    const int pb = g & 1;
    int sr = ar + 2; if (sr >= 3) sr -= 3;
    int nar = ar + 1; if (nar >= 3) nar = 0;
    const bool st = (g + 2 < NT);
#pragma unroll
    for (int p = 0; p < 4; ++p) {
      const int cs = p & 1, ns = cs ^ 1;
      if (p == 0) {
#pragma unroll
        for (int n = 0; n < 4; ++n) {
          bfr[n][0] = RD_B(pb, n, 0);
          bfr[n][1] = RD_B(pb, n, 1);
        }
      }
      asm volatile("s_waitcnt lgkmcnt(0)" ::: "memory");
      __builtin_amdgcn_sched_barrier(0);
      __builtin_amdgcn_s_setprio(1);
      MFMA_PAIR(2 * p, ap[cs][0])
      MFMA_PAIR(2 * p + 1, ap[cs][1])
      __builtin_amdgcn_s_setprio(0);
      if (p < 3) {
        ap[ns][0][0] = RD_A(ar, 2 * p + 2, 0); ap[ns][0][1] = RD_A(ar, 2 * p + 2, 1);
        ap[ns][1][0] = RD_A(ar, 2 * p + 3, 0); ap[ns][1][1] = RD_A(ar, 2 * p + 3, 1);
      } else if (g + 1 < NT) {
        ap[ns][0][0] = RD_A(nar, 0, 0); ap[ns][0][1] = RD_A(nar, 0, 1);
        ap[ns][1][0] = RD_A(nar, 1, 0); ap[ns][1][1] = RD_A(nar, 1, 1);
      }
      if (st) {
        if (p == 0) { STAGE_A(g + 2, sr, 0, 0); STAGE_A(g + 2, sr, 0, 1); }
        if (p == 1) { STAGE_A(g + 2, sr, 1, 0); STAGE_A(g + 2, sr, 1, 1); }
        if (p == 2) { STAGE_B(g + 2, 0, 0); STAGE_B(g + 2, 0, 1); }
        if (p == 3) { STAGE_B(g + 2, 1, 0); STAGE_B(g + 2, 1, 1); }
      }
      if (p == 2 && g + 1 < NT) {
        if (st) asm volatile("s_waitcnt vmcnt(6)" ::: "memory");
        else    asm volatile("s_waitcnt vmcnt(0)" ::: "memory");
      }
      asm volatile("s_barrier" ::: "memory");
    }
    ar = nar;
  }

  float bi[4];
#pragma unroll
  for (int n = 0; n < 4; ++n) bi[n] = bias[bcol + wc * 64 + n * 16 + fr];
  const long orow = brow + wr * 128 + fk * 4;
  const long ocol = bcol + wc * 64 + fr;
#pragma unroll
  for (int m = 0; m < 8; ++m)
#pragma unroll
    for (int n = 0; n < 4; ++n)
#pragma unroll
      for (int r = 0; r < 4; ++r) {
        float v = acc[m][n][r] + bi[n];
        v = v > 0.f ? v : 0.f;
        C[(orow + m * 16 + r) * (long)N + ocol + n * 16] = f2bf(v);
      }
#undef STAGE_A
#undef STAGE_B
#undef RD_A
#undef RD_B
#undef MFMA_PAIR
}

// ============ r9: 256x128-tile GEMM2 (r8 structure): Cf = (A@B^T + bias)*gamma + resid ============
// A [M,K]=h_act [8192,4096], B [N,K]=W2b [1024,4096]. Tile 256x128 -> grid 8x32=256
// blocks = exactly 1/CU, one round (256^2 would idle half the CUs at N=1024).
// 8 waves as 4M x 2N, per-wave out 64x64 (acc 4x4 f32x4 = 64 VGPR). BK=64, 64 K-tiles.
// LDS: A 3x32K @0/32/64K, B 2x16K @96K/112K = 128 KB. Same verified swizzle.
// Phases: p computes m=p (8 MFMA); A read-ahead ping-pong; B burst at ph0.
// Stages: ph0/ph1 A(g+2) x2 each, ph2 B(g+2) x2 -> 6 in flight; vmcnt(6) at ph2
// publishes tile g+1 (prologue: 12 loads, vmcnt(6) lands tile0's 6).
__global__ __launch_bounds__(512, 2) void gemm256_g2(
    const unsigned short* __restrict__ A, const unsigned short* __restrict__ B,
    float* __restrict__ Cf, const float* __restrict__ bias,
    const float* __restrict__ gamma, const float* __restrict__ resid,
    int M, int N, int K) {
  extern __shared__ char smem[];
  const int NT = K >> 6;

  const int nwg = gridDim.x;
  const int cpx = nwg >> 3;
  const int bid = blockIdx.x;
  const int swz = (bid & 7) * cpx + (bid >> 3);
  const int tiles_m = M >> 8;             // 32
  const int tm = swz % tiles_m;
  const int tn = swz / tiles_m;
  const long brow = (long)tm * 256;
  const long bcol = (long)tn * 128;

  const int t = threadIdx.x;
  const int lane = t & 63, wv = t >> 6;
  const int wr = wv >> 1, wc = wv & 1;    // 4M x 2N
  const int fr = lane & 15, fk = lane >> 4;

  const int srow = t >> 3;
  const int scol = 8 * ((t & 7) ^ ((t >> 3) & 7));
  const unsigned short* Asrc = A + (brow + srow) * (long)K + scol;
  const unsigned short* Bsrc = B + (bcol + srow) * (long)K + scol;
  const long hstep = (long)128 * K, lstep = (long)64 * K;

#define STAGE_A2(j, reg, h, L)                                                 \
  __builtin_amdgcn_global_load_lds(AS1(Asrc + (h)*hstep + (L)*lstep + (j)*64), \
      AS3(smem + (reg)*32768 + (h)*16384 + (L)*8192 + t * 16), 16, 0, 0)
#define STAGE_B2(j, L)                                                         \
  __builtin_amdgcn_global_load_lds(AS1(Bsrc + (L)*lstep + (j)*64),             \
      AS3(smem + 98304 + ((j)&1) * 16384 + (L)*8192 + t * 16), 16, 0, 0)

  const int xr = (fr & 7) << 4;
  const char* ArdRow = smem + (wr * 64 + fr) * 128;          // row = wr*64+m*16+fr
  const char* BrdRow = smem + 98304 + (wc * 64 + fr) * 128;  // row = wc*64+n*16+fr
#define RD_A2(ar_, m, kk) \
  (*(const s16x8*)(ArdRow + (ar_)*32768 + (m)*2048 + (((kk)*64 + fk * 16) ^ xr)))
#define RD_B2(pb_, n, kk) \
  (*(const s16x8*)(BrdRow + (pb_)*16384 + (n)*2048 + (((kk)*64 + fk * 16) ^ xr)))

  f32x4 acc[4][4];
#pragma unroll
  for (int m = 0; m < 4; m++)
#pragma unroll
    for (int n = 0; n < 4; n++) acc[m][n] = (f32x4)0.f;

  // prologue: A0(4), B0(2), A1(4), B1(2) = 12 loads; tile0 = first 6
  STAGE_A2(0, 0, 0, 0); STAGE_A2(0, 0, 0, 1); STAGE_A2(0, 0, 1, 0); STAGE_A2(0, 0, 1, 1);
  STAGE_B2(0, 0); STAGE_B2(0, 1);
  STAGE_A2(1, 1, 0, 0); STAGE_A2(1, 1, 0, 1); STAGE_A2(1, 1, 1, 0); STAGE_A2(1, 1, 1, 1);
  STAGE_B2(1, 0); STAGE_B2(1, 1);
  asm volatile("s_waitcnt vmcnt(6)" ::: "memory");
  __builtin_amdgcn_s_barrier();

  s16x8 bfr[4][2];
  s16x8 ap[2][2];  // [set][kk]
  ap[0][0] = RD_A2(0, 0, 0); ap[0][1] = RD_A2(0, 0, 1);

  int ar = 0;
  for (int g = 0; g < NT; ++g) {
    const int pb = g & 1;
    int sr = ar + 2; if (sr >= 3) sr -= 3;
    int nar = ar + 1; if (nar >= 3) nar = 0;
    const bool st = (g + 2 < NT);
#pragma unroll
    for (int p = 0; p < 4; ++p) {
      const int cs = p & 1, ns = cs ^ 1;
      if (p == 0) {
#pragma unroll
        for (int n = 0; n < 4; ++n) {
          bfr[n][0] = RD_B2(pb, n, 0);
          bfr[n][1] = RD_B2(pb, n, 1);
        }
      }
      asm volatile("s_waitcnt lgkmcnt(0)" ::: "memory");
      __builtin_amdgcn_sched_barrier(0);
      __builtin_amdgcn_s_setprio(1);
#pragma unroll
      for (int n = 0; n < 4; ++n) {
        acc[p][n] = __builtin_amdgcn_mfma_f32_16x16x32_bf16(
            ap[cs][0], bfr[n][0], acc[p][n], 0, 0, 0);
        acc[p][n] = __builtin_amdgcn_mfma_f32_16x16x32_bf16(
            ap[cs][1], bfr[n][1], acc[p][n], 0, 0, 0);
      }
      __builtin_amdgcn_s_setprio(0);
      if (p < 3) {
        ap[ns][0] = RD_A2(ar, p + 1, 0); ap[ns][1] = RD_A2(ar, p + 1, 1);
      } else if (g + 1 < NT) {
        ap[ns][0] = RD_A2(nar, 0, 0); ap[ns][1] = RD_A2(nar, 0, 1);
      }
      if (st) {
        if (p == 0) { STAGE_A2(g + 2, sr, 0, 0); STAGE_A2(g + 2, sr, 0, 1); }
        if (p == 1) { STAGE_A2(g + 2, sr, 1, 0); STAGE_A2(g + 2, sr, 1, 1); }
        if (p == 2) { STAGE_B2(g + 2, 0); STAGE_B2(g + 2, 1); }
      }
      if (p == 2 && g + 1 < NT) {
        if (st) asm volatile("s_waitcnt vmcnt(6)" ::: "memory");
        else    asm volatile("s_waitcnt vmcnt(0)" ::: "memory");
      }
      asm volatile("s_barrier" ::: "memory");
    }
    ar = nar;
  }

  // epilogue: (acc + bias) * gamma + resid -> fp32
  float bi[4], ga[4];
#pragma unroll
  for (int n = 0; n < 4; ++n) {
    const long col = bcol + wc * 64 + n * 16 + fr;
    bi[n] = bias[col];
    ga[n] = gamma[col];
  }
  const long orow = brow + wr * 64 + fk * 4;
  const long ocol = bcol + wc * 64 + fr;
#pragma unroll
  for (int m = 0; m < 4; ++m)
#pragma unroll
    for (int n = 0; n < 4; ++n)
#pragma unroll
      for (int r = 0; r < 4; ++r) {
        const long row = orow + m * 16 + r;
        const long col = ocol + n * 16;
        Cf[row * (long)N + col] = (acc[m][n][r] + bi[n]) * ga[n] + resid[row * (long)N + col];
      }
#undef STAGE_A2
#undef STAGE_B2
#undef RD_A2
#undef RD_B2
}

// ---------------- in-place LayerNorm over D=4096, one block per row ----------------
__global__ __launch_bounds__(256) void ln_inplace(unsigned short* __restrict__ h,
                                                  const float* __restrict__ w,
                                                  const float* __restrict__ b) {
  unsigned short* hp = h + (long)blockIdx.x * 4096;
  const int tid = threadIdx.x;
  u16x8 a0 = ((const u16x8*)hp)[tid * 2];
  u16x8 a1 = ((const u16x8*)hp)[tid * 2 + 1];
  float v[16];
#pragma unroll
  for (int j = 0; j < 8; j++) { v[j] = bf2f(a0[j]); v[8 + j] = bf2f(a1[j]); }
  float s = 0.f, q = 0.f;
#pragma unroll
  for (int j = 0; j < 16; j++) { s += v[j]; q += v[j] * v[j]; }
#pragma unroll
  for (int off = 32; off; off >>= 1) {
    s += __shfl_xor(s, off, 64);
    q += __shfl_xor(q, off, 64);
  }
  __shared__ float ss[4], sq[4];
  const int wv = tid >> 6;
  if ((tid & 63) == 0) { ss[wv] = s; sq[wv] = q; }
  __syncthreads();
  s = ss[0] + ss[1] + ss[2] + ss[3];
  q = sq[0] + sq[1] + sq[2] + sq[3];
  const float mu = s * (1.f / 4096.f);
  const float var = q * (1.f / 4096.f) - mu * mu;
  const float rs = rsqrtf(var + 1e-6f);
  u16x8 o0, o1;
#pragma unroll
  for (int j = 0; j < 8; j++) {
    int c0 = tid * 16 + j, c1 = c0 + 8;
    o0[j] = f2bf((v[j] - mu) * rs * w[c0] + b[c0]);
    o1[j] = f2bf((v[8 + j] - mu) * rs * w[c1] + b[c1]);
  }
  ((u16x8*)hp)[tid * 2] = o0;
  ((u16x8*)hp)[tid * 2 + 1] = o1;
}

extern "C" void kernel_launch(void* const* d_in, const int* in_sizes, int n_in,
                              void* d_out, int out_size, void* d_ws, size_t ws_size,
                              hipStream_t stream) {
  const float* x     = (const float*)d_in[0];
  const float* W1    = (const float*)d_in[1];
  const float* b1    = (const float*)d_in[2];
  const float* ln_w  = (const float*)d_in[3];
  const float* ln_b  = (const float*)d_in[4];
  const float* W2    = (const float*)d_in[5];
  const float* b2    = (const float*)d_in[6];
  const float* gamma = (const float*)d_in[7];
  float* out = (float*)d_out;

  const int Nr = 8192, DIM = 1024, DFF = 4096, K1 = 3072;

  unsigned short* W1b  = (unsigned short*)d_ws;
  unsigned short* W2b  = W1b + (long)DFF * K1;
  unsigned short* h_in = W2b + (long)DIM * DFF;
  unsigned short* h_act = h_in + (long)Nr * K1;
  float* partial = (float*)(h_act + (long)Nr * DFF);
  float* prefix  = partial + 128 * 1024;
  float* suffix  = prefix + 128 * 1024;

  hipFuncSetAttribute((const void*)gemm256_relu,
                      hipFuncAttributeMaxDynamicSharedMemorySize, 163840);
  hipFuncSetAttribute((const void*)gemm256_g2,
                      hipFuncAttributeMaxDynamicSharedMemorySize, 131072);

  cast_bf16<<<2048, 256, 0, stream>>>(W1, W1b, (long)DFF * K1);
  cast_bf16<<<1024, 256, 0, stream>>>(W2, W2b, (long)DIM * DFF);

  scan_chunkmax<<<dim3(4, 128), 256, 0, stream>>>(x, partial);
  scan_chunkscan<<<4, 256, 0, stream>>>(partial, prefix, suffix);
  scan_emit<<<dim3(4, 128), 256, 0, stream>>>(x, prefix, suffix, h_in);

  // GEMM1: h_act = relu(h_in @ W1^T + b1)  — 256^2 r8 structure, grid 512
  gemm256_relu<<<512, 512, 163840, stream>>>(h_in, W1b, h_act, b1, Nr, DFF, K1);

  ln_inplace<<<Nr, 256, 0, stream>>>(h_act, ln_w, ln_b);

  // GEMM2: out = (h_act @ W2^T + b2) * gamma + x  — 256x128 r9 structure, grid 256
  gemm256_g2<<<256, 512, 131072, stream>>>(h_act, W2b, out, b2, gamma, x,
                                           Nr, DIM, DFF);
}